// Round 12
// baseline (187.748 us; speedup 1.0000x reference)
//
#include <hip/hip_runtime.h>
#include <math.h>

#define DEV __device__ __forceinline__

typedef __attribute__((ext_vector_type(8))) short bf16x8;
typedef __attribute__((ext_vector_type(4))) float f32x4;

DEV float gelu_f(float x) { return 0.5f * x * (1.f + erff(x * 0.70710678118654752440f)); }

DEV unsigned short f2bf(float f) {
    unsigned u = __float_as_uint(f);
    u += 0x7FFF + ((u >> 16) & 1);
    return (unsigned short)(u >> 16);
}
DEV float bf2f(unsigned short h) { return __uint_as_float(((unsigned)h) << 16); }

// async global->LDS, 16B per lane; LDS dest = wave-uniform base + lane*16 (linear)
DEV void gload_lds16(const void* g, void* l) {
    __builtin_amdgcn_global_load_lds((const __attribute__((address_space(1))) void*)g,
                                     (__attribute__((address_space(3))) void*)l, 16, 0, 0);
}

// ---------------- MFMA GEMM body, LDS-staged, BK=64, plain bf16 ----------------
// C = act(A[M,K] @ W[N,K]^T + bias). T2 XOR-swizzle (slot^row&7); swz passed in.
// ASRC: 0 = A bf16 via gload_lds; 1 = A f32, reg-stage -> bf16 + ds_write.
// GATHER: A row m -> gidx[m] (ASRC=0 only).
// EPI: 0 none, 1 exact GELU.  OUT: 0 f32 C; 2 f32 C AND bf16 Ch; 3 bf16 Ch only.
template<int FM, int FN, int WR, int WC, int EPI, int GATHER, int ASRC, int OUT>
DEV void gemm_body(char* ldsbase, int swz,
                   const unsigned short* __restrict__ Ah, const float* __restrict__ Af,
                   const int* __restrict__ gidx,
                   const unsigned short* __restrict__ Wh, const float* __restrict__ bias,
                   float* __restrict__ C, unsigned short* __restrict__ Ch,
                   int ldsp, int coff, int M, int N, int K, int nbx)
{
    constexpr int BK = 64;
    constexpr int BM = WR * FM * 16, BN = WC * FN * 16;
    constexpr int NW = WR * WC;
    unsigned short* sAh = (unsigned short*)ldsbase;
    unsigned short* sWh = (unsigned short*)(ldsbase + BM * BK * 2);

    const int tid = threadIdx.x;
    const int lane = tid & 63;
    const int wid = tid >> 6;
    const int wr = wid / WC, wc = wid % WC;

    const int bx = swz % nbx, by = swz / nbx;
    const int row0 = by * BM;
    const int col0 = bx * BN;

    f32x4 acc[FM][FN];
#pragma unroll
    for (int i = 0; i < FM; i++)
#pragma unroll
        for (int j = 0; j < FN; j++) acc[i][j] = (f32x4){0.f, 0.f, 0.f, 0.f};

    const int srow = lane >> 3;
    const int sslot = lane & 7;

    for (int k0 = 0; k0 < K; k0 += BK) {
#pragma unroll
        for (int c = 0; c < BM / 8 / NW; c++) {
            int call = c * NW + wid;
            int r = call * 8 + srow;
            int gr = row0 + r;
            gr = gr < M ? gr : M - 1;
            if (ASRC == 0) {
                if (GATHER) gr = gidx[gr];
                int b = (sslot ^ (r & 7)) << 4;
                gload_lds16((const char*)(Ah + (size_t)gr * K + k0) + b, (char*)sAh + call * 1024);
            } else {
                const float* sp = Af + (size_t)gr * K + k0 + sslot * 8;
                float vv[8];
                *(float4*)&vv[0] = *(const float4*)sp;
                *(float4*)&vv[4] = *(const float4*)(sp + 4);
                union { bf16x8 v; unsigned short u[8]; } ph;
#pragma unroll
                for (int q = 0; q < 8; q++) ph.u[q] = f2bf(vv[q]);
                int b = (sslot ^ (r & 7)) << 4;
                *(bf16x8*)((char*)sAh + r * 128 + b) = ph.v;
            }
        }
#pragma unroll
        for (int c = 0; c < BN / 8 / NW; c++) {
            int call = c * NW + wid;
            int r = call * 8 + srow;
            int gr = col0 + r;
            int b = (sslot ^ (r & 7)) << 4;
            gload_lds16((const char*)(Wh + (size_t)gr * K + k0) + b, (char*)sWh + call * 1024);
        }
        __syncthreads();

        const int fr = lane & 15, kq = lane >> 4;
#pragma unroll
        for (int ks = 0; ks < 2; ks++) {
            bf16x8 ah[FM], bh[FN];
#pragma unroll
            for (int i = 0; i < FM; i++) {
                int r = wr * FM * 16 + i * 16 + fr;
                int b = ((ks * 4 + kq) ^ (r & 7)) << 4;
                ah[i] = *(const bf16x8*)((const char*)sAh + r * 128 + b);
            }
#pragma unroll
            for (int j = 0; j < FN; j++) {
                int r = wc * FN * 16 + j * 16 + fr;
                int b = ((ks * 4 + kq) ^ (r & 7)) << 4;
                bh[j] = *(const bf16x8*)((const char*)sWh + r * 128 + b);
            }
#pragma unroll
            for (int i = 0; i < FM; i++)
#pragma unroll
                for (int j = 0; j < FN; j++)
                    acc[i][j] = __builtin_amdgcn_mfma_f32_16x16x32_bf16(ah[i], bh[j], acc[i][j], 0, 0, 0);
        }
        __syncthreads();
    }

    const int fr = lane & 15;
    const int r0 = (lane >> 4) * 4;   // C/D: col = lane&15, row = (lane>>4)*4 + reg
#pragma unroll
    for (int i = 0; i < FM; i++) {
#pragma unroll
        for (int jj = 0; jj < 4; jj++) {
            int gr = row0 + wr * FM * 16 + i * 16 + r0 + jj;
            if (gr >= M) continue;
#pragma unroll
            for (int j = 0; j < FN; j++) {
                int gc = col0 + wc * FN * 16 + j * 16 + fr;
                float v = acc[i][j][jj] + (bias ? bias[gc] : 0.f);
                if (EPI == 1) v = gelu_f(v);
                if (OUT == 0 || OUT == 2) C[(size_t)gr * N + gc] = v;
                if (OUT == 2 || OUT == 3) Ch[(size_t)gr * ldsp + coff + gc] = f2bf(v);
            }
        }
    }
}

// bijective XCD swizzle for sub-grids with n % 8 == 0
DEV int xcd_swz(int bid, int nwg) {
    return ((nwg & 7) == 0) ? (bid & 7) * (nwg >> 3) + (bid >> 3) : bid;
}

// single-GEMM wrapper
template<int FM, int FN, int WR, int WC, int EPI, int GATHER, int ASRC, int OUT>
__global__ __launch_bounds__(WR* WC * 64)
void mgemm_k(const unsigned short* __restrict__ Ah, const float* __restrict__ Af,
             const int* __restrict__ gidx,
             const unsigned short* __restrict__ Wh, const float* __restrict__ bias,
             float* __restrict__ C, unsigned short* __restrict__ Ch,
             int ldsp, int coff, int M, int N, int K, int nbx)
{
    constexpr int BM = WR * FM * 16, BN = WC * FN * 16;
    __shared__ alignas(16) char lds[(BM + BN) * 64 * 2];
    int swz = xcd_swz(blockIdx.x, gridDim.x);
    gemm_body<FM, FN, WR, WC, EPI, GATHER, ASRC, OUT>(
        lds, swz, Ah, Af, gidx, Wh, bias, C, Ch, ldsp, coff, M, N, K, nbx);
}

// ---------------- fused tail: gate GEMM -> h_fused (LDS) -> sw1 GEMM -> score ----------------
// Each block: 32-row stripe x full 256 cols. 4 waves (wc = wid).
__global__ __launch_bounds__(256)
void tail_k(const unsigned short* __restrict__ gAh,     // [B,512] bf16
            const unsigned short* __restrict__ gaw_h,   // [256,512] bf16
            const float* __restrict__ gate_b,
            const float* __restrict__ h_sem, const float* __restrict__ h_struct, // [B,256] f32
            const float* __restrict__ heur, const float* __restrict__ heur_w,
            const float* __restrict__ heur_b, const float* __restrict__ hwp,
            const unsigned short* __restrict__ scw_h,   // [256,256] bf16
            const float* __restrict__ sb1, const float* __restrict__ sw2,
            const float* __restrict__ sb2, float* __restrict__ out, int B)
{
    __shared__ alignas(16) char lds[36864];
    unsigned short* sA = (unsigned short*)lds;            // [32][64] swz (4KB)
    unsigned short* sW = (unsigned short*)(lds + 4096);   // [256][64] swz (32KB)
    char* fu = lds + 4096;                                // [32][256] bf16 swz (16KB, phase2)
    float* sm = (float*)(lds + 20480);                    // [32][4] score partials

    const int tid = threadIdx.x;
    const int lane = tid & 63;
    const int wid = tid >> 6;
    const int swz = xcd_swz(blockIdx.x, gridDim.x);
    const int row0 = swz * 32;
    const int srow = lane >> 3, sslot = lane & 7;
    const int fr = lane & 15, kq = lane >> 4;

    // ---- phase 1: gate GEMM (K=512) ----
    f32x4 acc[2][4];
#pragma unroll
    for (int i = 0; i < 2; i++)
#pragma unroll
        for (int j = 0; j < 4; j++) acc[i][j] = (f32x4){0.f, 0.f, 0.f, 0.f};

    for (int k0 = 0; k0 < 512; k0 += 64) {
        {   // A: 1 call/wave
            int r = wid * 8 + srow;
            int b = (sslot ^ (r & 7)) << 4;
            gload_lds16((const char*)(gAh + (size_t)(row0 + r) * 512 + k0) + b, (char*)sA + wid * 1024);
        }
#pragma unroll
        for (int c = 0; c < 8; c++) {   // W: 8 calls/wave, 256 rows
            int call = c * 4 + wid;
            int r = call * 8 + srow;
            int b = (sslot ^ (r & 7)) << 4;
            gload_lds16((const char*)(gaw_h + (size_t)r * 512 + k0) + b, (char*)sW + call * 1024);
        }
        __syncthreads();
#pragma unroll
        for (int ks = 0; ks < 2; ks++) {
            bf16x8 ah[2], bh[4];
#pragma unroll
            for (int i = 0; i < 2; i++) {
                int r = i * 16 + fr;
                int b = ((ks * 4 + kq) ^ (r & 7)) << 4;
                ah[i] = *(const bf16x8*)((const char*)sA + r * 128 + b);
            }
#pragma unroll
            for (int j = 0; j < 4; j++) {
                int r = wid * 64 + j * 16 + fr;
                int b = ((ks * 4 + kq) ^ (r & 7)) << 4;
                bh[j] = *(const bf16x8*)((const char*)sW + r * 128 + b);
            }
#pragma unroll
            for (int i = 0; i < 2; i++)
#pragma unroll
                for (int j = 0; j < 4; j++)
                    acc[i][j] = __builtin_amdgcn_mfma_f32_16x16x32_bf16(ah[i], bh[j], acc[i][j], 0, 0, 0);
        }
        __syncthreads();
    }

    // ---- phase 1 epilogue: gate+heur+fusion -> h_fused bf16 into fu (swizzled) ----
    const int r0v = (lane >> 4) * 4;
    const float hwv = hwp[0];
#pragma unroll
    for (int i = 0; i < 2; i++) {
#pragma unroll
        for (int jj = 0; jj < 4; jj++) {
            int row = i * 16 + r0v + jj;
            int gr = row0 + row;
#pragma unroll
            for (int j = 0; j < 4; j++) {
                int gc = wid * 64 + j * 16 + fr;
                float v = acc[i][j][jj] + gate_b[gc];
                float g = 1.f / (1.f + expf(-v));
                float hh = heur_b[gc];
#pragma unroll
                for (int q = 0; q < 6; q++) hh = fmaf(heur[gr * 6 + q], heur_w[gc * 6 + q], hh);
                hh = gelu_f(hh);
                float hl = g * h_sem[(size_t)gr * 256 + gc] + (1.f - g) * h_struct[(size_t)gr * 256 + gc];
                v = hwv * hh + (1.f - hwv) * hl;
                int sub = gc >> 6, slot = (gc & 63) >> 3;
                int byteoff = row * 512 + sub * 128 + ((slot ^ (row & 7)) << 4) + (gc & 7) * 2;
                *(unsigned short*)(fu + byteoff) = f2bf(v);
            }
        }
    }
    __syncthreads();

    // ---- phase 2: sw1 GEMM (A from fu LDS, W direct from L2-hot scw) + score ----
    f32x4 acc2[2][4];
#pragma unroll
    for (int i = 0; i < 2; i++)
#pragma unroll
        for (int j = 0; j < 4; j++) acc2[i][j] = (f32x4){0.f, 0.f, 0.f, 0.f};

    for (int k0 = 0; k0 < 256; k0 += 32) {
        int sub = k0 >> 6;
        int slotb = ((k0 & 63) >> 3) + kq;   // 0..7
        bf16x8 ah2[2], bh2[4];
#pragma unroll
        for (int i = 0; i < 2; i++) {
            int r = i * 16 + fr;
            int byteoff = r * 512 + sub * 128 + ((slotb ^ (r & 7)) << 4);
            ah2[i] = *(const bf16x8*)(fu + byteoff);
        }
#pragma unroll
        for (int j = 0; j < 4; j++) {
            int gc = wid * 64 + j * 16 + fr;
            bh2[j] = *(const bf16x8*)(scw_h + (size_t)gc * 256 + k0 + kq * 8);
        }
#pragma unroll
        for (int i = 0; i < 2; i++)
#pragma unroll
            for (int j = 0; j < 4; j++)
                acc2[i][j] = __builtin_amdgcn_mfma_f32_16x16x32_bf16(ah2[i], bh2[j], acc2[i][j], 0, 0, 0);
    }

#pragma unroll
    for (int i = 0; i < 2; i++) {
#pragma unroll
        for (int jj = 0; jj < 4; jj++) {
            int row = i * 16 + r0v + jj;
            float sacc = 0.f;
#pragma unroll
            for (int j = 0; j < 4; j++) {
                int gc = wid * 64 + j * 16 + fr;
                float v = acc2[i][j][jj] + sb1[gc];
                v = gelu_f(v);
                sacc = fmaf(v, sw2[gc], sacc);
            }
            sacc += __shfl_xor(sacc, 1);
            sacc += __shfl_xor(sacc, 2);
            sacc += __shfl_xor(sacc, 4);
            sacc += __shfl_xor(sacc, 8);
            if ((lane & 15) == 0) sm[row * 4 + wid] = sacc;
        }
    }
    __syncthreads();
    if (tid < 32)
        out[row0 + tid] = sm[tid * 4 + 0] + sm[tid * 4 + 1] + sm[tid * 4 + 2] + sm[tid * 4 + 3] + sb2[0];
}

// ---------------- GAT softmax + aggregation body ----------------
DEV void gat_agg_body(char* shm, int d,
                      const int* __restrict__ ei, const float* __restrict__ ew,
                      const float* __restrict__ scal, const float* __restrict__ a_src,
                      const float* __restrict__ a_dst,
                      const int* __restrict__ count, const int* __restrict__ offs_end,
                      const int* __restrict__ eid, const unsigned short* __restrict__ xpb,
                      const float* __restrict__ gat_bias,
                      unsigned short* __restrict__ aggh, int E)
{
    int* srcs   = (int*)shm;               // 256 ints
    float* al   = (float*)(shm + 1024);    // 1024 floats
    float* mrun = (float*)(shm + 5120);
    float* drun = (float*)(shm + 5136);
    float* scale = (float*)(shm + 5152);
    int c = count[d];
    int start = offs_end[d] - c;
    int tid = threadIdx.x;
    if (tid < 4) { mrun[tid] = -1e30f; drun[tid] = 0.f; }
    float4 acc = make_float4(0.f, 0.f, 0.f, 0.f);
    const int h = tid >> 6;
    const int x = tid * 4;
    const float adst0 = a_dst[d * 4 + 0], adst1 = a_dst[d * 4 + 1],
                adst2 = a_dst[d * 4 + 2], adst3 = a_dst[d * 4 + 3];

    for (int cb = 0; cb < c; cb += 256) {
        int cc = min(256, c - cb);
        __syncthreads();
        for (int t = tid; t < cc * 4; t += 256) {
            int j = t >> 2, hh = t & 3;
            int e = eid[start + cb + j];
            int s; float ea;
            if (e < E) { s = ei[e]; ea = ew[e]; }
            else       { s = e - E; ea = scal[0] / (float)E; }
            float ad = hh == 0 ? adst0 : hh == 1 ? adst1 : hh == 2 ? adst2 : adst3;
            float a = a_src[s * 4 + hh] + ad + ea * scal[1 + hh];
            a = a > 0.f ? a : 0.2f * a;
            al[j * 4 + hh] = a;
            if (hh == 0) srcs[j] = s;
        }
        __syncthreads();
        if (tid < 4) {
            float m = -1e30f;
            for (int j = 0; j < cc; j++) m = fmaxf(m, al[j * 4 + tid]);
            float nm = fmaxf(mrun[tid], m);
            float sc = expf(mrun[tid] - nm);
            scale[tid] = sc;
            drun[tid] *= sc;
            mrun[tid] = nm;
        }
        __syncthreads();
        for (int t = tid; t < cc * 4; t += 256) {
            int j = t >> 2, hh = t & 3;
            al[j * 4 + hh] = expf(al[j * 4 + hh] - mrun[hh]);
        }
        __syncthreads();
        if (tid < 4) {
            float s = 0.f;
            for (int j = 0; j < cc; j++) s += al[j * 4 + tid];
            drun[tid] += s;
        }
        float sc = scale[h];
        acc.x *= sc; acc.y *= sc; acc.z *= sc; acc.w *= sc;
        for (int j = 0; j < cc; j++) {
            float w = al[j * 4 + h];
            ushort4 vv = *(const ushort4*)(xpb + (size_t)srcs[j] * 1024 + x);
            acc.x = fmaf(w, bf2f(vv.x), acc.x);
            acc.y = fmaf(w, bf2f(vv.y), acc.y);
            acc.z = fmaf(w, bf2f(vv.z), acc.z);
            acc.w = fmaf(w, bf2f(vv.w), acc.w);
        }
    }
    __syncthreads();
    float dn = drun[h];
    float4 gb = *(const float4*)(gat_bias + x);
    float t0 = acc.x / dn + gb.x, t1 = acc.y / dn + gb.y,
          t2 = acc.z / dn + gb.z, t3 = acc.w / dn + gb.w;
    t0 = t0 > 0.f ? t0 : expf(t0) - 1.f;
    t1 = t1 > 0.f ? t1 : expf(t1) - 1.f;
    t2 = t2 > 0.f ? t2 : expf(t2) - 1.f;
    t3 = t3 > 0.f ? t3 : expf(t3) - 1.f;
    ushort4 hh;
    hh.x = f2bf(t0); hh.y = f2bf(t1); hh.z = f2bf(t2); hh.w = f2bf(t3);
    *(ushort4*)(aggh + (size_t)d * 1024 + x) = hh;
}

// dual A: x_proj (bf16, 128x128) || sem1 (bf16, 32x64, f32-A, GELU) || CSR fill
__global__ __launch_bounds__(256)
void dualA_k(const unsigned short* __restrict__ gxh, const unsigned short* __restrict__ linw_h,
             unsigned short* __restrict__ xpb, int Nn, int HC, int DIN, int nbx_x, int nxp,
             const float* __restrict__ sem, const unsigned short* __restrict__ sw1w_h,
             const float* __restrict__ sem_b1, unsigned short* __restrict__ s1h,
             int B, int nbh, int nh1,
             const int* __restrict__ ei, int* __restrict__ offs, int* __restrict__ eid, int E)
{
    __shared__ alignas(16) char lds[32768];   // max(x_proj 32KB, sem1 12KB) -> 5 blocks/CU
    int bid = blockIdx.x;
    if (bid < nxp) {
        int swz = xcd_swz(bid, nxp);
        gemm_body<4, 4, 2, 2, 0, 0, 0, 3>(
            lds, swz, gxh, nullptr, nullptr, linw_h, nullptr,
            nullptr, xpb, HC, 0, Nn, HC, DIN, nbx_x);
    } else if (bid < nxp + nh1) {
        int swz = xcd_swz(bid - nxp, nh1);
        gemm_body<1, 2, 2, 2, 1, 0, 1, 3>(
            lds, swz, nullptr, sem, nullptr, sw1w_h, sem_b1,
            nullptr, s1h, 256, 0, B, 256, 2 * DIN, nbh);
    } else {
        int e = (bid - nxp - nh1) * 256 + threadIdx.x;
        if (e < E + Nn) {
            int d = (e < E) ? ei[E + e] : e - E;
            int p = atomicAdd(&offs[d], 1);
            eid[p] = e;
        }
    }
}

// dual C: gat_agg (Nn blocks) || sem2 GEMM (bf16, K=256, f32 h_sem + bf16 gA[:,0:256])
__global__ __launch_bounds__(256)
void dualC_k(int Nn, int nh1,
             const int* __restrict__ ei, const float* __restrict__ ew,
             const float* __restrict__ scal, const float* __restrict__ a_src,
             const float* __restrict__ a_dst, const int* __restrict__ needed,
             const int* __restrict__ count, const int* __restrict__ offs_end,
             const int* __restrict__ eid, const unsigned short* __restrict__ xpb,
             const float* __restrict__ gat_bias,
             unsigned short* __restrict__ aggh, int E,
             const unsigned short* __restrict__ s1h,
             const unsigned short* __restrict__ sw2w_h,
             const float* __restrict__ sem_b2, float* __restrict__ h_sem,
             unsigned short* __restrict__ gAh,
             int B, int nbh)
{
    __shared__ alignas(16) char lds[12288];
    int bid = blockIdx.x;
    if (bid < Nn) {
        if (!needed[bid]) return;
        gat_agg_body(lds, bid, ei, ew, scal, a_src, a_dst, count, offs_end, eid,
                     xpb, gat_bias, aggh, E);
    } else {
        int swz = xcd_swz(bid - Nn, nh1);
        gemm_body<1, 2, 2, 2, 0, 0, 0, 2>(
            lds, swz, s1h, nullptr, nullptr, sw2w_h, sem_b2,
            h_sem, gAh, 512, 0, B, 256, 256, nbh);
    }
}

// ---------------- setup kernels ----------------

// zero count/needed/scal[0]/cursor + rank-1 wprep + scal[1..4]
__global__ void init_k(int* count, int* needed, float* scal, int Nn,
                       const float* __restrict__ lin_w, const float* __restrict__ att_src,
                       const float* __restrict__ att_dst,
                       float* __restrict__ wsrc, float* __restrict__ wdst,
                       const float* __restrict__ lew, const float* __restrict__ ae, int ZB,
                       int* __restrict__ cursor)
{
    int b = blockIdx.x;
    if (b < ZB) {
        int i = b * 256 + threadIdx.x;
        if (i < Nn) { count[i] = 0; needed[i] = 0; }
        if (i == 0) { scal[0] = 0.f; cursor[0] = 0; }
        return;
    }
    if (b < ZB + 12) {
        int gid = (b - ZB) * 256 + threadIdx.x;
        if (gid >= 4 * 768) return;
        int h = gid / 768, k = gid % 768;
        float ss = 0.f, sd = 0.f;
        for (int c = 0; c < 256; c++) {
            float w = lin_w[(size_t)(h * 256 + c) * 768 + k];
            ss = fmaf(w, att_src[h * 256 + c], ss);
            sd = fmaf(w, att_dst[h * 256 + c], sd);
        }
        wsrc[k * 4 + h] = ss;
        wdst[k * 4 + h] = sd;
        return;
    }
    int w = threadIdx.x / 64, lane = threadIdx.x % 64;
    float c = 0.f;
    for (int cc = lane; cc < 256; cc += 64) c += lew[w * 256 + cc] * ae[w * 256 + cc];
    for (int off = 32; off; off >>= 1) c += __shfl_down(c, off);
    if (lane == 0) scal[1 + w] = c;
}

// mega: cvtadot (Nn) | weight-cvt hi-only (nW) | count-all (nCnt) | mark (nMark) | ew-sum (nEw)
__global__ __launch_bounds__(256)
void mega1_k(int Nn, int nW, int nCnt, int nMark, int nEw,
             const float* __restrict__ gx, unsigned short* __restrict__ gxh,
             const float* __restrict__ wsrc, const float* __restrict__ wdst,
             float* __restrict__ a_src, float* __restrict__ a_dst,
             const float* s0, unsigned short* h0, int e0,
             const float* s1, unsigned short* h1, int e1,
             const float* s2, unsigned short* h2, int e2,
             const float* s3, unsigned short* h3, int e3,
             const float* s4, unsigned short* h4, int e4,
             const float* s5, unsigned short* h5, int e5,
             const int* __restrict__ ei, int* __restrict__ count, int E,
             const int* __restrict__ nidx, int* __restrict__ needed, int B,
             const float* __restrict__ ew, float* __restrict__ scal)
{
    __shared__ float sh[256];
    int b = blockIdx.x;
    int t = threadIdx.x;

    if (b < Nn) {
        int node = b;
        float acc[8] = {0.f, 0.f, 0.f, 0.f, 0.f, 0.f, 0.f, 0.f};
        if (t < 192) {
            float4 v = ((const float4*)(gx + (size_t)node * 768))[t];
            ushort4 h;
            h.x = f2bf(v.x); h.y = f2bf(v.y); h.z = f2bf(v.z); h.w = f2bf(v.w);
            ((ushort4*)(gxh + (size_t)node * 768))[t] = h;
            float vv[4] = {v.x, v.y, v.z, v.w};
#pragma unroll
            for (int q = 0; q < 4; q++) {
                int k = t * 4 + q;
                float4 wsv = *(const float4*)(wsrc + k * 4);
                float4 wdv = *(const float4*)(wdst + k * 4);
                acc[0] = fmaf(vv[q], wsv.x, acc[0]); acc[1] = fmaf(vv[q], wsv.y, acc[1]);
                acc[2] = fmaf(vv[q], wsv.z, acc[2]); acc[3] = fmaf(vv[q], wsv.w, acc[3]);
                acc[4] = fmaf(vv[q], wdv.x, acc[4]); acc[5] = fmaf(vv[q], wdv.y, acc[5]);
                acc[6] = fmaf(vv[q], wdv.z, acc[6]); acc[7] = fmaf(vv[q], wdv.w, acc[7]);
            }
        }
#pragma unroll
        for (int i = 0; i < 8; i++)
            for (int off = 32; off; off >>= 1) acc[i] += __shfl_down(acc[i], off);
        int lane = t & 63, wid = t >> 6;
        if (lane == 0)
#pragma unroll
            for (int i = 0; i < 8; i++) sh[wid * 8 + i] = acc[i];
        __syncthreads();
        if (t < 8) {
            float s = sh[t] + sh[8 + t] + sh[16 + t] + sh[24 + t];
            if (t < 4) a_src[node * 4 + t] = s;
            else       a_dst[node * 4 + (t - 4)] = s;
        }
        return;
    }
    b -= Nn;
    if (b < nW) {
        int i = b * 256 + t;
        const float* s; unsigned short* h; int j;
        if (i < e0)      { s = s0; h = h0; j = i; }
        else if (i < e1) { s = s1; h = h1; j = i - e0; }
        else if (i < e2) { s = s2; h = h2; j = i - e1; }
        else if (i < e3) { s = s3; h = h3; j = i - e2; }
        else if (i < e4) { s = s4; h = h4; j = i - e3; }
        else if (i < e5) { s = s5; h = h5; j = i - e4; }
        else return;
        float4 v = ((const float4*)s)[j];
        ushort4 hh;
        hh.x = f2bf(v.x); hh.y = f2bf(v.y); hh.z = f2bf(v.z); hh.w = f2bf(v.w);
        ((ushort4*)h)[j] = hh;
        return;
    }
    b -= nW;
    if (b < nCnt) {
        int e = b * 256 + t;
        if (e >= E + Nn) return;
        int d = (e < E) ? ei[E + e] : e - E;
        atomicAdd(&count[d], 1);
        return;
    }
    b -= nCnt;
    if (b < nMark) {
        int gid = b * 256 + t;
        if (gid < B) needed[nidx[gid]] = 1;
        return;
    }
    b -= nMark;
    float s = 0.f;
    for (int i = b * 256 + t; i < E; i += nEw * 256) s += ew[i];
    sh[t] = s;
    __syncthreads();
    for (int off = 128; off; off >>= 1) {
        if (t < off) sh[t] += sh[t + off];
        __syncthreads();
    }
    if (t == 0) atomicAdd(&scal[0], sh[0]);
}

// parallel segment allocation
__global__ void alloc_k(const int* __restrict__ count, int* __restrict__ offs,
                        int* __restrict__ cursor, int Nn)
{
    int d = blockIdx.x * 256 + threadIdx.x;
    if (d < Nn) offs[d] = atomicAdd(cursor, count[d]);
}

// ---------------- launch ----------------

extern "C" void kernel_launch(void* const* d_in, const int* in_sizes, int n_in,
                              void* d_out, int out_size, void* d_ws, size_t ws_size,
                              hipStream_t stream)
{
    const float* sem      = (const float*)d_in[0];
    const float* gx       = (const float*)d_in[1];
    const int*   ei       = (const int*)d_in[2];
    const float* ew       = (const float*)d_in[3];
    const float* heur     = (const float*)d_in[4];
    const int*   nidx     = (const int*)d_in[5];
    const float* sem_w1   = (const float*)d_in[6];
    const float* sem_b1   = (const float*)d_in[7];
    const float* sem_w2   = (const float*)d_in[8];
    const float* sem_b2   = (const float*)d_in[9];
    const float* lin_w    = (const float*)d_in[10];
    const float* lin_edge = (const float*)d_in[11];
    const float* att_src  = (const float*)d_in[12];
    const float* att_dst  = (const float*)d_in[13];
    const float* att_edge = (const float*)d_in[14];
    const float* gat_bias = (const float*)d_in[15];
    const float* struct_w = (const float*)d_in[16];
    const float* struct_b = (const float*)d_in[17];
    const float* gate_w   = (const float*)d_in[18];
    const float* gate_b   = (const float*)d_in[19];
    const float* heur_w   = (const float*)d_in[20];
    const float* heur_b   = (const float*)d_in[21];
    const float* hwp      = (const float*)d_in[22];
    const float* sw1      = (const float*)d_in[23];
    const float* sb1      = (const float*)d_in[24];
    const float* sw2      = (const float*)d_in[25];
    const float* sb2      = (const float*)d_in[26];
    float* out = (float*)d_out;

    const int DIN = 768, HC = 1024, HID = 256;
    const int B  = in_sizes[0] / (2 * DIN);
    const int Nn = in_sizes[1] / DIN;
    const int E  = in_sizes[3];

    float* ws = (float*)d_ws;
    size_t off = 0;
    auto alloc = [&](size_t n) { float* p = ws + off; off += n; return p; };
    auto allocU = [&](size_t nelem) { return (unsigned short*)alloc((nelem + 1) / 2); };

    unsigned short* xpb  = allocU((size_t)Nn * HC);      // x_proj bf16 [N,1024]
    unsigned short* aggh = allocU((size_t)Nn * HC);      // elu(agg+bias) bf16
    float* h_sem    = alloc((size_t)B * HID);
    float* h_struct = alloc((size_t)B * HID);
    unsigned short* s1h = allocU((size_t)B * HID);       // sem hidden bf16
    unsigned short* gAh = allocU((size_t)B * 512);       // concat(h_sem,h_struct) bf16
    float* a_src    = alloc((size_t)Nn * 4);
    float* a_dst    = alloc((size_t)Nn * 4);
    float* wsrc     = alloc((size_t)DIN * 4);
    float* wdst     = alloc((size_t)DIN * 4);
    int* countb     = (int*)alloc((size_t)Nn);
    int* offsb      = (int*)alloc((size_t)Nn);
    int* neededb    = (int*)alloc((size_t)Nn);
    int* eidb       = (int*)alloc((size_t)(E + Nn));
    float* scal     = alloc(8);
    int* cursorb    = (int*)alloc(4);
    // weight bf16 (hi only)
    unsigned short* linw_h = allocU((size_t)HC * DIN);
    unsigned short* sw1w_h = allocU((size_t)HID * 2 * DIN);
    unsigned short* sw2w_h = allocU((size_t)HID * HID);
    unsigned short* stw_h  = allocU((size_t)HID * HC);
    unsigned short* gaw_h  = allocU((size_t)HID * 512);
    unsigned short* scw_h  = allocU((size_t)HID * HID);
    unsigned short* gxh    = allocU((size_t)Nn * DIN);
    (void)ws_size; (void)n_in; (void)out_size;

    // --- init: zero + rank-1 att prep + scal[1..4] ---
    int ZB = (Nn + 255) / 256;
    init_k<<<ZB + 13, 256, 0, stream>>>(countb, neededb, scal, Nn,
                                        lin_w, att_src, att_dst, wsrc, wdst,
                                        lin_edge, att_edge, ZB, cursorb);

    // --- mega1: cvtadot | weight cvt | count-all | mark | ew-sum ---
    int c0 = (HC * DIN) / 4;
    int c1 = c0 + (HID * 2 * DIN) / 4;
    int c2 = c1 + (HID * HID) / 4;
    int c3 = c2 + (HID * HC) / 4;
    int c4 = c3 + (HID * 512) / 4;
    int c5 = c4 + (HID * HID) / 4;
    int nW = (c5 + 255) / 256;
    int tot = E + Nn;
    int nCnt = (tot + 255) / 256;
    int nMark = (B + 255) / 256;
    int nEw = 256;
    mega1_k<<<Nn + nW + nCnt + nMark + nEw, 256, 0, stream>>>(
        Nn, nW, nCnt, nMark, nEw,
        gx, gxh, wsrc, wdst, a_src, a_dst,
        lin_w, linw_h, c0,
        sem_w1, sw1w_h, c1,
        sem_w2, sw2w_h, c2,
        struct_w, stw_h, c3,
        gate_w, gaw_h, c4,
        sw1, scw_h, c5,
        ei, countb, E,
        nidx, neededb, B,
        ew, scal);

    // --- parallel segment allocation ---
    alloc_k<<<(Nn + 255) / 256, 256, 0, stream>>>(countb, offsb, cursorb, Nn);

    // --- dual A: x_proj || sem1 || CSR fill ---
    const int nbx_x = HC / 128;                   // 8
    const int nby_x = (Nn + 127) / 128;           // 79
    const int nxp = nbx_x * nby_x;                // 632
    const int nbh = HID / 64;                     // 4
    const int nh1 = (B / 32) * nbh;               // 512
    const int nF = (tot + 255) / 256;             // 665
    dualA_k<<<nxp + nh1 + nF, 256, 0, stream>>>(gxh, linw_h, xpb, Nn, HC, DIN, nbx_x, nxp,
                                                sem, sw1w_h, sem_b1, s1h,
                                                B, nbh, nh1, ei, offsb, eidb, E);

    // --- dual C: gat_agg || sem2 ---
    dualC_k<<<Nn + nh1, 256, 0, stream>>>(Nn, nh1,
                                          ei, ew, scal, a_src, a_dst, neededb, countb, offsb, eidb,
                                          xpb, gat_bias, aggh, E,
                                          s1h, sw2w_h, sem_b2, h_sem, gAh, B, nbh);

    // --- struct (plain bf16): h_struct f32 + bf16 gA[:,256:512] ---
    mgemm_k<1, 2, 2, 2, 1, 1, 0, 2><<<nh1, 256, 0, stream>>>(
        aggh, nullptr, nidx, stw_h, struct_b,
        h_struct, gAh, 512, 256, B, HID, HC, nbh);

    // --- fused tail: gate -> h_fused (LDS) -> sw1 -> score ---
    tail_k<<<B / 32, 256, 0, stream>>>(gAh, gaw_h, gate_b, h_sem, h_struct,
                                       heur, heur_w, heur_b, hwp,
                                       scw_h, sb1, sw2, sb2, out, B);
}

// Round 13
// 178.970 us; speedup vs baseline: 1.0490x; 1.0490x over previous
//
#include <hip/hip_runtime.h>
#include <math.h>

#define DEV __device__ __forceinline__

typedef __attribute__((ext_vector_type(8))) short bf16x8;
typedef __attribute__((ext_vector_type(4))) float f32x4;

DEV float gelu_f(float x) { return 0.5f * x * (1.f + erff(x * 0.70710678118654752440f)); }

DEV unsigned short f2bf(float f) {
    unsigned u = __float_as_uint(f);
    u += 0x7FFF + ((u >> 16) & 1);
    return (unsigned short)(u >> 16);
}
DEV float bf2f(unsigned short h) { return __uint_as_float(((unsigned)h) << 16); }

// async global->LDS, 16B per lane; LDS dest = wave-uniform base + lane*16 (linear)
DEV void gload_lds16(const void* g, void* l) {
    __builtin_amdgcn_global_load_lds((const __attribute__((address_space(1))) void*)g,
                                     (__attribute__((address_space(3))) void*)l, 16, 0, 0);
}

// ---------------- MFMA GEMM body, LDS-staged, BK=64, plain bf16 ----------------
// C = act(A[M,K] @ W[N,K]^T + bias). T2 XOR-swizzle (slot^row&7); swz passed in.
// ASRC: 0 = A bf16 via gload_lds; 1 = A f32, reg-stage -> bf16 + ds_write.
// GATHER: A row m -> gidx[m] (ASRC=0 only).
// EPI: 0 none, 1 exact GELU, 3 fused gate+heur+fusion.
// OUT: 0 f32 C; 2 f32 C AND bf16 Ch; 3 bf16 Ch only; 4 fused score:
//      atomicAdd(&C[gr], sum_gc v*fs_hsem[gc]) via 16-lane shfl reduce (fs_hsem = sw2).
template<int FM, int FN, int WR, int WC, int EPI, int GATHER, int ASRC, int OUT>
DEV void gemm_body(char* ldsbase, int swz,
                   const unsigned short* __restrict__ Ah, const float* __restrict__ Af,
                   const int* __restrict__ gidx,
                   const unsigned short* __restrict__ Wh, const float* __restrict__ bias,
                   float* __restrict__ C, unsigned short* __restrict__ Ch,
                   int ldsp, int coff,
                   const float* __restrict__ fs_hsem, const float* __restrict__ fs_hstruct,
                   const float* __restrict__ fs_heur, const float* __restrict__ fs_heurw,
                   const float* __restrict__ fs_heurb, const float* __restrict__ fs_hw,
                   int M, int N, int K, int nbx)
{
    constexpr int BK = 64;
    constexpr int BM = WR * FM * 16, BN = WC * FN * 16;
    constexpr int NW = WR * WC;
    unsigned short* sAh = (unsigned short*)ldsbase;
    unsigned short* sWh = (unsigned short*)(ldsbase + BM * BK * 2);

    const int tid = threadIdx.x;
    const int lane = tid & 63;
    const int wid = tid >> 6;
    const int wr = wid / WC, wc = wid % WC;

    const int bx = swz % nbx, by = swz / nbx;
    const int row0 = by * BM;
    const int col0 = bx * BN;

    f32x4 acc[FM][FN];
#pragma unroll
    for (int i = 0; i < FM; i++)
#pragma unroll
        for (int j = 0; j < FN; j++) acc[i][j] = (f32x4){0.f, 0.f, 0.f, 0.f};

    const int srow = lane >> 3;
    const int sslot = lane & 7;

    for (int k0 = 0; k0 < K; k0 += BK) {
#pragma unroll
        for (int c = 0; c < BM / 8 / NW; c++) {
            int call = c * NW + wid;
            int r = call * 8 + srow;
            int gr = row0 + r;
            gr = gr < M ? gr : M - 1;
            if (ASRC == 0) {
                if (GATHER) gr = gidx[gr];
                int b = (sslot ^ (r & 7)) << 4;
                gload_lds16((const char*)(Ah + (size_t)gr * K + k0) + b, (char*)sAh + call * 1024);
            } else {
                const float* sp = Af + (size_t)gr * K + k0 + sslot * 8;
                float vv[8];
                *(float4*)&vv[0] = *(const float4*)sp;
                *(float4*)&vv[4] = *(const float4*)(sp + 4);
                union { bf16x8 v; unsigned short u[8]; } ph;
#pragma unroll
                for (int q = 0; q < 8; q++) ph.u[q] = f2bf(vv[q]);
                int b = (sslot ^ (r & 7)) << 4;
                *(bf16x8*)((char*)sAh + r * 128 + b) = ph.v;
            }
        }
#pragma unroll
        for (int c = 0; c < BN / 8 / NW; c++) {
            int call = c * NW + wid;
            int r = call * 8 + srow;
            int gr = col0 + r;
            int b = (sslot ^ (r & 7)) << 4;
            gload_lds16((const char*)(Wh + (size_t)gr * K + k0) + b, (char*)sWh + call * 1024);
        }
        __syncthreads();

        const int fr = lane & 15, kq = lane >> 4;
#pragma unroll
        for (int ks = 0; ks < 2; ks++) {
            bf16x8 ah[FM], bh[FN];
#pragma unroll
            for (int i = 0; i < FM; i++) {
                int r = wr * FM * 16 + i * 16 + fr;
                int b = ((ks * 4 + kq) ^ (r & 7)) << 4;
                ah[i] = *(const bf16x8*)((const char*)sAh + r * 128 + b);
            }
#pragma unroll
            for (int j = 0; j < FN; j++) {
                int r = wc * FN * 16 + j * 16 + fr;
                int b = ((ks * 4 + kq) ^ (r & 7)) << 4;
                bh[j] = *(const bf16x8*)((const char*)sWh + r * 128 + b);
            }
#pragma unroll
            for (int i = 0; i < FM; i++)
#pragma unroll
                for (int j = 0; j < FN; j++)
                    acc[i][j] = __builtin_amdgcn_mfma_f32_16x16x32_bf16(ah[i], bh[j], acc[i][j], 0, 0, 0);
        }
        __syncthreads();
    }

    const int fr = lane & 15;
    const int r0 = (lane >> 4) * 4;   // C/D: col = lane&15, row = (lane>>4)*4 + reg
#pragma unroll
    for (int i = 0; i < FM; i++) {
#pragma unroll
        for (int jj = 0; jj < 4; jj++) {
            int gr = row0 + wr * FM * 16 + i * 16 + r0 + jj;
            if (gr >= M) continue;
            float sacc = 0.f;
#pragma unroll
            for (int j = 0; j < FN; j++) {
                int gc = col0 + wc * FN * 16 + j * 16 + fr;
                float v = acc[i][j][jj] + (bias ? bias[gc] : 0.f);
                if (EPI == 1) v = gelu_f(v);
                else if (EPI == 3) {
                    float g = 1.f / (1.f + expf(-v));
                    float hh = fs_heurb[gc];
#pragma unroll
                    for (int q = 0; q < 6; q++) hh = fmaf(fs_heur[gr * 6 + q], fs_heurw[gc * 6 + q], hh);
                    hh = gelu_f(hh);
                    float hl = g * fs_hsem[(size_t)gr * 256 + gc] + (1.f - g) * fs_hstruct[(size_t)gr * 256 + gc];
                    float hwv = fs_hw[0];
                    v = hwv * hh + (1.f - hwv) * hl;
                }
                if (OUT == 0 || OUT == 2) C[(size_t)gr * N + gc] = v;
                if (OUT == 2 || OUT == 3) Ch[(size_t)gr * ldsp + coff + gc] = f2bf(v);
                if (OUT == 4) sacc = fmaf(v, fs_hsem[gc], sacc);
            }
            if (OUT == 4) {
                sacc += __shfl_xor(sacc, 1);
                sacc += __shfl_xor(sacc, 2);
                sacc += __shfl_xor(sacc, 4);
                sacc += __shfl_xor(sacc, 8);
                if ((lane & 15) == 0) atomicAdd(&C[gr], sacc);
            }
        }
    }
}

// bijective XCD swizzle for sub-grids with n % 8 == 0
DEV int xcd_swz(int bid, int nwg) {
    return ((nwg & 7) == 0) ? (bid & 7) * (nwg >> 3) + (bid >> 3) : bid;
}

// single-GEMM wrapper
template<int FM, int FN, int WR, int WC, int EPI, int GATHER, int ASRC, int OUT>
__global__ __launch_bounds__(WR* WC * 64)
void mgemm_k(const unsigned short* __restrict__ Ah, const float* __restrict__ Af,
             const int* __restrict__ gidx,
             const unsigned short* __restrict__ Wh, const float* __restrict__ bias,
             float* __restrict__ C, unsigned short* __restrict__ Ch,
             int ldsp, int coff,
             const float* __restrict__ fs_hsem, const float* __restrict__ fs_hstruct,
             const float* __restrict__ fs_heur, const float* __restrict__ fs_heurw,
             const float* __restrict__ fs_heurb, const float* __restrict__ fs_hw,
             int M, int N, int K, int nbx)
{
    constexpr int BM = WR * FM * 16, BN = WC * FN * 16;
    __shared__ alignas(16) char lds[(BM + BN) * 64 * 2];
    int swz = xcd_swz(blockIdx.x, gridDim.x);
    gemm_body<FM, FN, WR, WC, EPI, GATHER, ASRC, OUT>(
        lds, swz, Ah, Af, gidx, Wh, bias, C, Ch, ldsp, coff,
        fs_hsem, fs_hstruct, fs_heur, fs_heurw, fs_heurb, fs_hw, M, N, K, nbx);
}

// ---------------- GAT softmax + aggregation body ----------------
DEV void gat_agg_body(char* shm, int d,
                      const int* __restrict__ ei, const float* __restrict__ ew,
                      const float* __restrict__ scal, const float* __restrict__ a_src,
                      const float* __restrict__ a_dst,
                      const int* __restrict__ count, const int* __restrict__ offs_end,
                      const int* __restrict__ eid, const unsigned short* __restrict__ xpb,
                      const float* __restrict__ gat_bias,
                      unsigned short* __restrict__ aggh, int E)
{
    int* srcs   = (int*)shm;               // 256 ints
    float* al   = (float*)(shm + 1024);    // 1024 floats
    float* mrun = (float*)(shm + 5120);
    float* drun = (float*)(shm + 5136);
    float* scale = (float*)(shm + 5152);
    int c = count[d];
    int start = offs_end[d] - c;
    int tid = threadIdx.x;
    if (tid < 4) { mrun[tid] = -1e30f; drun[tid] = 0.f; }
    float4 acc = make_float4(0.f, 0.f, 0.f, 0.f);
    const int h = tid >> 6;
    const int x = tid * 4;
    const float adst0 = a_dst[d * 4 + 0], adst1 = a_dst[d * 4 + 1],
                adst2 = a_dst[d * 4 + 2], adst3 = a_dst[d * 4 + 3];

    for (int cb = 0; cb < c; cb += 256) {
        int cc = min(256, c - cb);
        __syncthreads();
        for (int t = tid; t < cc * 4; t += 256) {
            int j = t >> 2, hh = t & 3;
            int e = eid[start + cb + j];
            int s; float ea;
            if (e < E) { s = ei[e]; ea = ew[e]; }
            else       { s = e - E; ea = scal[0] / (float)E; }
            float ad = hh == 0 ? adst0 : hh == 1 ? adst1 : hh == 2 ? adst2 : adst3;
            float a = a_src[s * 4 + hh] + ad + ea * scal[1 + hh];
            a = a > 0.f ? a : 0.2f * a;
            al[j * 4 + hh] = a;
            if (hh == 0) srcs[j] = s;
        }
        __syncthreads();
        if (tid < 4) {
            float m = -1e30f;
            for (int j = 0; j < cc; j++) m = fmaxf(m, al[j * 4 + tid]);
            float nm = fmaxf(mrun[tid], m);
            float sc = expf(mrun[tid] - nm);
            scale[tid] = sc;
            drun[tid] *= sc;
            mrun[tid] = nm;
        }
        __syncthreads();
        for (int t = tid; t < cc * 4; t += 256) {
            int j = t >> 2, hh = t & 3;
            al[j * 4 + hh] = expf(al[j * 4 + hh] - mrun[hh]);
        }
        __syncthreads();
        if (tid < 4) {
            float s = 0.f;
            for (int j = 0; j < cc; j++) s += al[j * 4 + tid];
            drun[tid] += s;
        }
        float sc = scale[h];
        acc.x *= sc; acc.y *= sc; acc.z *= sc; acc.w *= sc;
        for (int j = 0; j < cc; j++) {
            float w = al[j * 4 + h];
            ushort4 vv = *(const ushort4*)(xpb + (size_t)srcs[j] * 1024 + x);
            acc.x = fmaf(w, bf2f(vv.x), acc.x);
            acc.y = fmaf(w, bf2f(vv.y), acc.y);
            acc.z = fmaf(w, bf2f(vv.z), acc.z);
            acc.w = fmaf(w, bf2f(vv.w), acc.w);
        }
    }
    __syncthreads();
    float dn = drun[h];
    float4 gb = *(const float4*)(gat_bias + x);
    float t0 = acc.x / dn + gb.x, t1 = acc.y / dn + gb.y,
          t2 = acc.z / dn + gb.z, t3 = acc.w / dn + gb.w;
    t0 = t0 > 0.f ? t0 : expf(t0) - 1.f;
    t1 = t1 > 0.f ? t1 : expf(t1) - 1.f;
    t2 = t2 > 0.f ? t2 : expf(t2) - 1.f;
    t3 = t3 > 0.f ? t3 : expf(t3) - 1.f;
    ushort4 hh;
    hh.x = f2bf(t0); hh.y = f2bf(t1); hh.z = f2bf(t2); hh.w = f2bf(t3);
    *(ushort4*)(aggh + (size_t)d * 1024 + x) = hh;
}

// dual A: x_proj (bf16, 128x128) || sem1 (bf16, 32x64, f32-A, GELU) || CSR fill
__global__ __launch_bounds__(256)
void dualA_k(const unsigned short* __restrict__ gxh, const unsigned short* __restrict__ linw_h,
             unsigned short* __restrict__ xpb, int Nn, int HC, int DIN, int nbx_x, int nxp,
             const float* __restrict__ sem, const unsigned short* __restrict__ sw1w_h,
             const float* __restrict__ sem_b1, unsigned short* __restrict__ s1h,
             int B, int nbh, int nh1,
             const int* __restrict__ ei, int* __restrict__ offs, int* __restrict__ eid, int E)
{
    __shared__ alignas(16) char lds[32768];   // max(x_proj 32KB, sem1 12KB) -> 5 blocks/CU
    int bid = blockIdx.x;
    if (bid < nxp) {
        int swz = xcd_swz(bid, nxp);
        gemm_body<4, 4, 2, 2, 0, 0, 0, 3>(
            lds, swz, gxh, nullptr, nullptr, linw_h, nullptr,
            nullptr, xpb, HC, 0, nullptr, nullptr, nullptr, nullptr, nullptr, nullptr,
            Nn, HC, DIN, nbx_x);
    } else if (bid < nxp + nh1) {
        int swz = xcd_swz(bid - nxp, nh1);
        gemm_body<1, 2, 2, 2, 1, 0, 1, 3>(
            lds, swz, nullptr, sem, nullptr, sw1w_h, sem_b1,
            nullptr, s1h, 256, 0, nullptr, nullptr, nullptr, nullptr, nullptr, nullptr,
            B, 256, 2 * DIN, nbh);
    } else {
        int e = (bid - nxp - nh1) * 256 + threadIdx.x;
        if (e < E + Nn) {
            int d = (e < E) ? ei[E + e] : e - E;
            int p = atomicAdd(&offs[d], 1);
            eid[p] = e;
        }
    }
}

// dual C: gat_agg (Nn blocks) || sem2 GEMM (bf16, K=256, f32 h_sem + bf16 gA[:,0:256])
__global__ __launch_bounds__(256)
void dualC_k(int Nn, int nh1,
             const int* __restrict__ ei, const float* __restrict__ ew,
             const float* __restrict__ scal, const float* __restrict__ a_src,
             const float* __restrict__ a_dst, const int* __restrict__ needed,
             const int* __restrict__ count, const int* __restrict__ offs_end,
             const int* __restrict__ eid, const unsigned short* __restrict__ xpb,
             const float* __restrict__ gat_bias,
             unsigned short* __restrict__ aggh, int E,
             const unsigned short* __restrict__ s1h,
             const unsigned short* __restrict__ sw2w_h,
             const float* __restrict__ sem_b2, float* __restrict__ h_sem,
             unsigned short* __restrict__ gAh,
             int B, int nbh)
{
    __shared__ alignas(16) char lds[12288];
    int bid = blockIdx.x;
    if (bid < Nn) {
        if (!needed[bid]) return;
        gat_agg_body(lds, bid, ei, ew, scal, a_src, a_dst, count, offs_end, eid,
                     xpb, gat_bias, aggh, E);
    } else {
        int swz = xcd_swz(bid - Nn, nh1);
        gemm_body<1, 2, 2, 2, 0, 0, 0, 2>(
            lds, swz, s1h, nullptr, nullptr, sw2w_h, sem_b2,
            h_sem, gAh, 512, 0, nullptr, nullptr, nullptr, nullptr, nullptr, nullptr,
            B, 256, 256, nbh);
    }
}

// ---------------- setup kernels ----------------

// zero count/needed/scal[0]/cursor + out=sb2 + rank-1 wprep + scal[1..4]
__global__ void init_k(int* count, int* needed, float* scal, int Nn,
                       const float* __restrict__ lin_w, const float* __restrict__ att_src,
                       const float* __restrict__ att_dst,
                       float* __restrict__ wsrc, float* __restrict__ wdst,
                       const float* __restrict__ lew, const float* __restrict__ ae, int ZB,
                       float* __restrict__ out, const float* __restrict__ sb2, int B,
                       int* __restrict__ cursor)
{
    int b = blockIdx.x;
    if (b < ZB) {
        int i = b * 256 + threadIdx.x;
        if (i < Nn) { count[i] = 0; needed[i] = 0; }
        if (i < B) out[i] = sb2[0];
        if (i == 0) { scal[0] = 0.f; cursor[0] = 0; }
        return;
    }
    if (b < ZB + 12) {
        int gid = (b - ZB) * 256 + threadIdx.x;
        if (gid >= 4 * 768) return;
        int h = gid / 768, k = gid % 768;
        float ss = 0.f, sd = 0.f;
        for (int c = 0; c < 256; c++) {
            float w = lin_w[(size_t)(h * 256 + c) * 768 + k];
            ss = fmaf(w, att_src[h * 256 + c], ss);
            sd = fmaf(w, att_dst[h * 256 + c], sd);
        }
        wsrc[k * 4 + h] = ss;
        wdst[k * 4 + h] = sd;
        return;
    }
    int w = threadIdx.x / 64, lane = threadIdx.x % 64;
    float c = 0.f;
    for (int cc = lane; cc < 256; cc += 64) c += lew[w * 256 + cc] * ae[w * 256 + cc];
    for (int off = 32; off; off >>= 1) c += __shfl_down(c, off);
    if (lane == 0) scal[1 + w] = c;
}

// mega: cvtadot (Nn) | weight-cvt hi-only (nW) | count-all (nCnt) | mark (nMark) | ew-sum (nEw)
__global__ __launch_bounds__(256)
void mega1_k(int Nn, int nW, int nCnt, int nMark, int nEw,
             const float* __restrict__ gx, unsigned short* __restrict__ gxh,
             const float* __restrict__ wsrc, const float* __restrict__ wdst,
             float* __restrict__ a_src, float* __restrict__ a_dst,
             const float* s0, unsigned short* h0, int e0,
             const float* s1, unsigned short* h1, int e1,
             const float* s2, unsigned short* h2, int e2,
             const float* s3, unsigned short* h3, int e3,
             const float* s4, unsigned short* h4, int e4,
             const float* s5, unsigned short* h5, int e5,
             const int* __restrict__ ei, int* __restrict__ count, int E,
             const int* __restrict__ nidx, int* __restrict__ needed, int B,
             const float* __restrict__ ew, float* __restrict__ scal)
{
    __shared__ float sh[256];
    int b = blockIdx.x;
    int t = threadIdx.x;

    if (b < Nn) {
        int node = b;
        float acc[8] = {0.f, 0.f, 0.f, 0.f, 0.f, 0.f, 0.f, 0.f};
        if (t < 192) {
            float4 v = ((const float4*)(gx + (size_t)node * 768))[t];
            ushort4 h;
            h.x = f2bf(v.x); h.y = f2bf(v.y); h.z = f2bf(v.z); h.w = f2bf(v.w);
            ((ushort4*)(gxh + (size_t)node * 768))[t] = h;
            float vv[4] = {v.x, v.y, v.z, v.w};
#pragma unroll
            for (int q = 0; q < 4; q++) {
                int k = t * 4 + q;
                float4 wsv = *(const float4*)(wsrc + k * 4);
                float4 wdv = *(const float4*)(wdst + k * 4);
                acc[0] = fmaf(vv[q], wsv.x, acc[0]); acc[1] = fmaf(vv[q], wsv.y, acc[1]);
                acc[2] = fmaf(vv[q], wsv.z, acc[2]); acc[3] = fmaf(vv[q], wsv.w, acc[3]);
                acc[4] = fmaf(vv[q], wdv.x, acc[4]); acc[5] = fmaf(vv[q], wdv.y, acc[5]);
                acc[6] = fmaf(vv[q], wdv.z, acc[6]); acc[7] = fmaf(vv[q], wdv.w, acc[7]);
            }
        }
#pragma unroll
        for (int i = 0; i < 8; i++)
            for (int off = 32; off; off >>= 1) acc[i] += __shfl_down(acc[i], off);
        int lane = t & 63, wid = t >> 6;
        if (lane == 0)
#pragma unroll
            for (int i = 0; i < 8; i++) sh[wid * 8 + i] = acc[i];
        __syncthreads();
        if (t < 8) {
            float s = sh[t] + sh[8 + t] + sh[16 + t] + sh[24 + t];
            if (t < 4) a_src[node * 4 + t] = s;
            else       a_dst[node * 4 + (t - 4)] = s;
        }
        return;
    }
    b -= Nn;
    if (b < nW) {
        int i = b * 256 + t;
        const float* s; unsigned short* h; int j;
        if (i < e0)      { s = s0; h = h0; j = i; }
        else if (i < e1) { s = s1; h = h1; j = i - e0; }
        else if (i < e2) { s = s2; h = h2; j = i - e1; }
        else if (i < e3) { s = s3; h = h3; j = i - e2; }
        else if (i < e4) { s = s4; h = h4; j = i - e3; }
        else if (i < e5) { s = s5; h = h5; j = i - e4; }
        else return;
        float4 v = ((const float4*)s)[j];
        ushort4 hh;
        hh.x = f2bf(v.x); hh.y = f2bf(v.y); hh.z = f2bf(v.z); hh.w = f2bf(v.w);
        ((ushort4*)h)[j] = hh;
        return;
    }
    b -= nW;
    if (b < nCnt) {
        int e = b * 256 + t;
        if (e >= E + Nn) return;
        int d = (e < E) ? ei[E + e] : e - E;
        atomicAdd(&count[d], 1);
        return;
    }
    b -= nCnt;
    if (b < nMark) {
        int gid = b * 256 + t;
        if (gid < B) needed[nidx[gid]] = 1;
        return;
    }
    b -= nMark;
    float s = 0.f;
    for (int i = b * 256 + t; i < E; i += nEw * 256) s += ew[i];
    sh[t] = s;
    __syncthreads();
    for (int off = 128; off; off >>= 1) {
        if (t < off) sh[t] += sh[t + off];
        __syncthreads();
    }
    if (t == 0) atomicAdd(&scal[0], sh[0]);
}

// parallel segment allocation
__global__ void alloc_k(const int* __restrict__ count, int* __restrict__ offs,
                        int* __restrict__ cursor, int Nn)
{
    int d = blockIdx.x * 256 + threadIdx.x;
    if (d < Nn) offs[d] = atomicAdd(cursor, count[d]);
}

// ---------------- launch ----------------

extern "C" void kernel_launch(void* const* d_in, const int* in_sizes, int n_in,
                              void* d_out, int out_size, void* d_ws, size_t ws_size,
                              hipStream_t stream)
{
    const float* sem      = (const float*)d_in[0];
    const float* gx       = (const float*)d_in[1];
    const int*   ei       = (const int*)d_in[2];
    const float* ew       = (const float*)d_in[3];
    const float* heur     = (const float*)d_in[4];
    const int*   nidx     = (const int*)d_in[5];
    const float* sem_w1   = (const float*)d_in[6];
    const float* sem_b1   = (const float*)d_in[7];
    const float* sem_w2   = (const float*)d_in[8];
    const float* sem_b2   = (const float*)d_in[9];
    const float* lin_w    = (const float*)d_in[10];
    const float* lin_edge = (const float*)d_in[11];
    const float* att_src  = (const float*)d_in[12];
    const float* att_dst  = (const float*)d_in[13];
    const float* att_edge = (const float*)d_in[14];
    const float* gat_bias = (const float*)d_in[15];
    const float* struct_w = (const float*)d_in[16];
    const float* struct_b = (const float*)d_in[17];
    const float* gate_w   = (const float*)d_in[18];
    const float* gate_b   = (const float*)d_in[19];
    const float* heur_w   = (const float*)d_in[20];
    const float* heur_b   = (const float*)d_in[21];
    const float* hwp      = (const float*)d_in[22];
    const float* sw1      = (const float*)d_in[23];
    const float* sb1      = (const float*)d_in[24];
    const float* sw2      = (const float*)d_in[25];
    const float* sb2      = (const float*)d_in[26];
    float* out = (float*)d_out;

    const int DIN = 768, HC = 1024, HID = 256;
    const int B  = in_sizes[0] / (2 * DIN);
    const int Nn = in_sizes[1] / DIN;
    const int E  = in_sizes[3];

    float* ws = (float*)d_ws;
    size_t off = 0;
    auto alloc = [&](size_t n) { float* p = ws + off; off += n; return p; };
    auto allocU = [&](size_t nelem) { return (unsigned short*)alloc((nelem + 1) / 2); };

    unsigned short* xpb  = allocU((size_t)Nn * HC);      // x_proj bf16 [N,1024]
    unsigned short* aggh = allocU((size_t)Nn * HC);      // elu(agg+bias) bf16
    float* h_sem    = alloc((size_t)B * HID);
    float* h_struct = alloc((size_t)B * HID);
    unsigned short* s1h = allocU((size_t)B * HID);       // sem hidden bf16
    unsigned short* gAh = allocU((size_t)B * 512);       // concat(h_sem,h_struct) bf16
    unsigned short* fuh = allocU((size_t)B * HID);       // h_fused bf16
    float* a_src    = alloc((size_t)Nn * 4);
    float* a_dst    = alloc((size_t)Nn * 4);
    float* wsrc     = alloc((size_t)DIN * 4);
    float* wdst     = alloc((size_t)DIN * 4);
    int* countb     = (int*)alloc((size_t)Nn);
    int* offsb      = (int*)alloc((size_t)Nn);
    int* neededb    = (int*)alloc((size_t)Nn);
    int* eidb       = (int*)alloc((size_t)(E + Nn));
    float* scal     = alloc(8);
    int* cursorb    = (int*)alloc(4);
    // weight bf16 (hi only)
    unsigned short* linw_h = allocU((size_t)HC * DIN);
    unsigned short* sw1w_h = allocU((size_t)HID * 2 * DIN);
    unsigned short* sw2w_h = allocU((size_t)HID * HID);
    unsigned short* stw_h  = allocU((size_t)HID * HC);
    unsigned short* gaw_h  = allocU((size_t)HID * 512);
    unsigned short* scw_h  = allocU((size_t)HID * HID);
    unsigned short* gxh    = allocU((size_t)Nn * DIN);
    (void)ws_size; (void)n_in; (void)out_size;

    // --- init: zero + out=sb2 + rank-1 att prep + scal[1..4] ---
    int ZB = (Nn + 255) / 256;
    init_k<<<ZB + 13, 256, 0, stream>>>(countb, neededb, scal, Nn,
                                        lin_w, att_src, att_dst, wsrc, wdst,
                                        lin_edge, att_edge, ZB, out, sb2, B, cursorb);

    // --- mega1: cvtadot | weight cvt | count-all | mark | ew-sum ---
    int c0 = (HC * DIN) / 4;
    int c1 = c0 + (HID * 2 * DIN) / 4;
    int c2 = c1 + (HID * HID) / 4;
    int c3 = c2 + (HID * HC) / 4;
    int c4 = c3 + (HID * 512) / 4;
    int c5 = c4 + (HID * HID) / 4;
    int nW = (c5 + 255) / 256;
    int tot = E + Nn;
    int nCnt = (tot + 255) / 256;
    int nMark = (B + 255) / 256;
    int nEw = 256;
    mega1_k<<<Nn + nW + nCnt + nMark + nEw, 256, 0, stream>>>(
        Nn, nW, nCnt, nMark, nEw,
        gx, gxh, wsrc, wdst, a_src, a_dst,
        lin_w, linw_h, c0,
        sem_w1, sw1w_h, c1,
        sem_w2, sw2w_h, c2,
        struct_w, stw_h, c3,
        gate_w, gaw_h, c4,
        sw1, scw_h, c5,
        ei, countb, E,
        nidx, neededb, B,
        ew, scal);

    // --- parallel segment allocation ---
    alloc_k<<<(Nn + 255) / 256, 256, 0, stream>>>(countb, offsb, cursorb, Nn);

    // --- dual A: x_proj || sem1 || CSR fill ---
    const int nbx_x = HC / 128;                   // 8
    const int nby_x = (Nn + 127) / 128;           // 79
    const int nxp = nbx_x * nby_x;                // 632
    const int nbh = HID / 64;                     // 4
    const int nh1 = (B / 32) * nbh;               // 512
    const int nF = (tot + 255) / 256;             // 665
    dualA_k<<<nxp + nh1 + nF, 256, 0, stream>>>(gxh, linw_h, xpb, Nn, HC, DIN, nbx_x, nxp,
                                                sem, sw1w_h, sem_b1, s1h,
                                                B, nbh, nh1, ei, offsb, eidb, E);

    // --- dual C: gat_agg || sem2 ---
    dualC_k<<<Nn + nh1, 256, 0, stream>>>(Nn, nh1,
                                          ei, ew, scal, a_src, a_dst, neededb, countb, offsb, eidb,
                                          xpb, gat_bias, aggh, E,
                                          s1h, sw2w_h, sem_b2, h_sem, gAh, B, nbh);

    // --- struct (plain bf16): h_struct f32 + bf16 gA[:,256:512] ---
    mgemm_k<1, 2, 2, 2, 1, 1, 0, 2><<<nh1, 256, 0, stream>>>(
        aggh, nullptr, nidx, stw_h, struct_b,
        h_struct, gAh, 512, 256, nullptr, nullptr, nullptr, nullptr, nullptr, nullptr,
        B, HID, HC, nbh);

    // --- gate GEMM (plain bf16) with fused heur + fusion epilogue -> bf16 fuh ---
    mgemm_k<1, 2, 2, 2, 3, 0, 0, 3><<<nh1, 256, 0, stream>>>(
        gAh, nullptr, nullptr, gaw_h, gate_b,
        nullptr, fuh, HID, 0, h_sem, h_struct, heur, heur_w, heur_b, hwp,
        B, HID, 512, nbh);

    // --- sw1 GEMM (plain bf16) with fused score: out[b] += sum_gc gelu(...)*sw2[gc] ---
    mgemm_k<1, 2, 2, 2, 1, 0, 0, 4><<<nh1, 256, 0, stream>>>(
        fuh, nullptr, nullptr, scw_h, sb1,
        out, nullptr, 0, 0, sw2, nullptr, nullptr, nullptr, nullptr, nullptr,
        B, HID, HID, nbh);
}